// Round 1
// baseline (327.758 us; speedup 1.0000x reference)
//
#include <hip/hip_runtime.h>

// SSIM fused kernel for B=16, C=3, H=W=768, 11-tap separable Gaussian, VALID.
// Output: per-batch mean SSIM [16] (fp32).
//
// Structure: blocks own a (strip of 256 output cols) x (row segment).
// Stage A: horizontal blur of 5 quantities, global->regs (4 cols/thread), h row -> LDS.
// Stage B: vertical blur via per-thread register ring (1 col/thread, 14-deep, 4 rows/iter).
// Reduction: wave shuffle + LDS + one atomicAdd per block into d_out (zeroed by kernel 0).

#define H_IMG 768
#define W_IMG 768
#define OH 758
#define OW_TOT 758
#define OWS 256   // output cols per strip
#define NSEG 8    // vertical segments

__global__ void ssim_zero_out(float* __restrict__ out) {
    if (threadIdx.x < 16) out[threadIdx.x] = 0.0f;
}

__launch_bounds__(256, 3)
__global__ void ssim_fused(const float* __restrict__ X, const float* __restrict__ Y,
                           const float* __restrict__ Wg, float* __restrict__ out) {
    const float C1 = 1e-4f, C2 = 9e-4f, EPS = 1e-8f;
    const float INV_COUNT = 1.0f / (3.0f * 758.0f * 758.0f);

    const int t = threadIdx.x;
    int bx = blockIdx.x;
    const int seg = bx & 7; bx >>= 3;
    const int strip = bx % 3; bx /= 3;
    const int ch = bx % 3;
    const int b  = bx / 3;

    const int R0 = (OH * seg) / NSEG;        // first output row of segment
    const int R1 = (OH * (seg + 1)) / NSEG;  // one past last
    const int c0 = strip * OWS;

    const float* Xi = X + (size_t)(b * 3 + ch) * (H_IMG * W_IMG);
    const float* Yi = Y + (size_t)(b * 3 + ch) * (H_IMG * W_IMG);

    float w[11];
#pragma unroll
    for (int k = 0; k < 11; ++k) w[k] = Wg[k];

    __shared__ float hbuf[4][5][OWS];   // 20 KB: h rows handoff A->B
    __shared__ float red[4];

    // Stage A mapping: 4 rows x 64 col-groups (4 cols each)
    const int sA = t >> 6;
    const int cg = t & 63;
    const int colbase = c0 + 4 * cg;
    // Clamped, alignment-preserving load bases (clamped data only feeds
    // predicated-off outputs; see per-case analysis in session notes).
    const int k0 = min(colbase,      W_IMG - 4);
    const int k1 = min(colbase + 4,  W_IMG - 4);
    const int k2 = min(colbase + 8,  W_IMG - 4);
    const int k3 = min(colbase + 12, W_IMG - 2);

    // Stage B: register ring, 14 h-rows x 5 quantities
    float ring[5][14];
#pragma unroll
    for (int q = 0; q < 5; ++q)
#pragma unroll
        for (int j = 0; j < 14; ++j) ring[q][j] = 0.0f;

    float local = 0.0f;
    const int M = (R1 - R0 + 13) >> 2;  // macro-iters of 4 input rows

    for (int m = 0; m < M; ++m) {
        // ---------------- Stage A: horizontal blur ----------------
        {
            int r = R0 + 4 * m + sA;
            r = min(r, H_IMG - 1);
            const float* xr = Xi + (size_t)r * W_IMG;
            const float* yr = Yi + (size_t)r * W_IMG;
            float4 xa = *(const float4*)(xr + k0);
            float4 xb = *(const float4*)(xr + k1);
            float4 xc = *(const float4*)(xr + k2);
            float2 xd = *(const float2*)(xr + k3);
            float4 ya = *(const float4*)(yr + k0);
            float4 yb = *(const float4*)(yr + k1);
            float4 yc = *(const float4*)(yr + k2);
            float2 yd = *(const float2*)(yr + k3);
            float xv[14] = {xa.x, xa.y, xa.z, xa.w, xb.x, xb.y, xb.z, xb.w,
                            xc.x, xc.y, xc.z, xc.w, xd.x, xd.y};
            float yv[14] = {ya.x, ya.y, ya.z, ya.w, yb.x, yb.y, yb.z, yb.w,
                            yc.x, yc.y, yc.z, yc.w, yd.x, yd.y};

            float h0[4] = {0,0,0,0}, h1[4] = {0,0,0,0}, h4[4] = {0,0,0,0};
#pragma unroll
            for (int k = 0; k < 11; ++k)
#pragma unroll
                for (int cc = 0; cc < 4; ++cc) {
                    h0[cc] = fmaf(w[k], xv[cc + k], h0[cc]);
                    h1[cc] = fmaf(w[k], yv[cc + k], h1[cc]);
                    h4[cc] = fmaf(w[k], xv[cc + k] * yv[cc + k], h4[cc]);
                }
#pragma unroll
            for (int p = 0; p < 14; ++p) { xv[p] *= xv[p]; yv[p] *= yv[p]; }
            float h2[4] = {0,0,0,0}, h3[4] = {0,0,0,0};
#pragma unroll
            for (int k = 0; k < 11; ++k)
#pragma unroll
                for (int cc = 0; cc < 4; ++cc) {
                    h2[cc] = fmaf(w[k], xv[cc + k], h2[cc]);
                    h3[cc] = fmaf(w[k], yv[cc + k], h3[cc]);
                }
            *(float4*)&hbuf[sA][0][4 * cg] = make_float4(h0[0], h0[1], h0[2], h0[3]);
            *(float4*)&hbuf[sA][1][4 * cg] = make_float4(h1[0], h1[1], h1[2], h1[3]);
            *(float4*)&hbuf[sA][2][4 * cg] = make_float4(h2[0], h2[1], h2[2], h2[3]);
            *(float4*)&hbuf[sA][3][4 * cg] = make_float4(h3[0], h3[1], h3[2], h3[3]);
            *(float4*)&hbuf[sA][4][4 * cg] = make_float4(h4[0], h4[1], h4[2], h4[3]);
        }
        __syncthreads();

        // ---------------- Stage B: vertical blur + SSIM ----------------
        {
#pragma unroll
            for (int q = 0; q < 5; ++q)
#pragma unroll
                for (int j = 0; j < 10; ++j) ring[q][j] = ring[q][j + 4];
#pragma unroll
            for (int s2 = 0; s2 < 4; ++s2)
#pragma unroll
                for (int q = 0; q < 5; ++q)
                    ring[q][10 + s2] = hbuf[s2][q][t];

            const bool colok = (c0 + t) < OW_TOT;
#pragma unroll
            for (int s2 = 0; s2 < 4; ++s2) {
                const int orow = R0 + 4 * m - 10 + s2;
                float a0 = 0.f, a1 = 0.f, a2 = 0.f, a3 = 0.f, a4 = 0.f;
#pragma unroll
                for (int k = 0; k < 11; ++k) {
                    a0 = fmaf(w[k], ring[0][s2 + k], a0);
                    a1 = fmaf(w[k], ring[1][s2 + k], a1);
                    a2 = fmaf(w[k], ring[2][s2 + k], a2);
                    a3 = fmaf(w[k], ring[3][s2 + k], a3);
                    a4 = fmaf(w[k], ring[4][s2 + k], a4);
                }
                float sx  = a2 - a0 * a0;
                float sy  = a3 - a1 * a1;
                float sxy = a4 - a0 * a1;
                float cs = __fdividef(2.0f * sxy + C2, sx + sy + C2 + EPS);
                cs = fmaxf(cs, 0.0f);
                float l = __fdividef(2.0f * a0 * a1 + C1,
                                     a0 * a0 + a1 * a1 + C1 + EPS);
                float v = l * cs;
                if (colok && (orow >= R0) && (orow < R1)) local += v;
            }
        }
        __syncthreads();
    }

    // ---------------- block reduction + atomic ----------------
    float v = local;
#pragma unroll
    for (int off = 32; off > 0; off >>= 1) v += __shfl_down(v, off, 64);
    if ((t & 63) == 0) red[t >> 6] = v;
    __syncthreads();
    if (t == 0) {
        atomicAdd(&out[b], (red[0] + red[1] + red[2] + red[3]) * INV_COUNT);
    }
}

extern "C" void kernel_launch(void* const* d_in, const int* in_sizes, int n_in,
                              void* d_out, int out_size, void* d_ws, size_t ws_size,
                              hipStream_t stream) {
    const float* X  = (const float*)d_in[0];
    const float* Y  = (const float*)d_in[1];
    const float* Wg = (const float*)d_in[2];
    float* out = (float*)d_out;

    hipLaunchKernelGGL(ssim_zero_out, dim3(1), dim3(64), 0, stream, out);
    hipLaunchKernelGGL(ssim_fused, dim3(16 * 3 * 3 * NSEG), dim3(256), 0, stream,
                       X, Y, Wg, out);
}